// Round 16
// baseline (95.176 us; speedup 1.0000x reference)
//
#include <hip/hip_runtime.h>
#include <hip/hip_fp16.h>

// VQC statevector simulator, v16 = v12 BYTE-EXACT RESUBMIT (re-anchor).
// v13/v14/v15 (single-sample restructures) all failed correctness with
// deterministic wrong answers; v13 vs v14 differ only in launch bounds yet
// give different wrong answers (compilation implicated), v14 vs v15 differ
// structurally yet give identical wrong answers. Maps re-derived and proven
// self-consistent; sample-A dataflow in v15 was line-identical to v12 ->
// suspected codegen/hazard interaction (inline-asm pk_fma -> DPP chains)
// invisible at source level. Per pre-commitment: revert to v12 permanently.
//
// v12: pipelined 2-sample fp16 + op_sel RX + SGPR coefficient preload +
// fused final-butterfly sweep write + DPP EXPECT levels. PASSED: 94.8us,
// absmax 7.8e-3, VGPR 128, zero spill.

typedef unsigned int u32;

constexpr int NQ  = 14;
constexpr int DIM = 1 << NQ;     // 16384
constexpr int NT  = 512;         // 8 waves
constexpr int APT = DIM / NT;    // 32
constexpr int NL  = 4;

#define H2U(v) __builtin_bit_cast(u32, v)
#define U2H(v) __builtin_bit_cast(__half2, v)
// quad_perm lane^1 = 0xB1, lane^2 = 0x4E
#define DPP1(v) U2H((u32)__builtin_amdgcn_mov_dpp((int)H2U(v), 0xB1, 0xF, 0xF, true))
#define DPP2(v) U2H((u32)__builtin_amdgcn_mov_dpp((int)H2U(v), 0x4E, 0xF, 0xF, true))
#define DPPF1(v) __builtin_bit_cast(float, (u32)__builtin_amdgcn_mov_dpp((int)__builtin_bit_cast(u32, v), 0xB1, 0xF, 0xF, true))
#define DPPF2(v) __builtin_bit_cast(float, (u32)__builtin_amdgcn_mov_dpp((int)__builtin_bit_cast(u32, v), 0x4E, 0xF, 0xF, true))
// EXPECT cross-lane: levels 0,1 via DPP (VALU), rest via shfl (LDS crossbar)
#define SHX(V, K) ((K) == 0 ? DPPF1(V) : (K) == 1 ? DPPF2(V) : __shfl_xor((V), 1 << (K), 64))

// d.lo = s.lo*p.hi + t.lo ; d.hi = s.hi*p.lo + t.hi  (swap fused via op_sel)
static __device__ __forceinline__ __half2 fma_sw(__half2 s, __half2 p, __half2 t) {
    u32 d, su = H2U(s), pu = H2U(p), tu = H2U(t);
    asm("v_pk_fma_f16 %0, %1, %2, %3 op_sel:[0,1,0] op_sel_hi:[1,0,1]"
        : "=v"(d) : "v"(su), "v"(pu), "v"(tu));
    return U2H(d);
}

// Preload 7 qubits' (sp,cc) of layer L starting at qubit Q0 into SGPR arrays.
// Issued at the END of the previous phase: the pre-barrier lgkmcnt(0) covers
// the wait, so the next phase's RX has no LDS dependency.
#define PRELOADW(L, Q0) { _Pragma("unroll")                             \
    for (int i_ = 0; i_ < 7; ++i_) {                                    \
        uint2 w_ = wtab[(L) * NQ + (Q0) + i_];                          \
        sw[i_] = __builtin_amdgcn_readfirstlane((int)w_.x);             \
        cw[i_] = __builtin_amdgcn_readfirstlane((int)w_.y); } }

#define RXQs(ARR, QBIT, I) {                                            \
    const __half2 sp_ = U2H((u32)sw[I]), cc_ = U2H((u32)cw[I]);         \
    _Pragma("unroll")                                                   \
    for (int o = 0; o < APT; ++o) {                                     \
        if (o & (1 << (QBIT))) continue;                                \
        const int o1_ = o | (1 << (QBIT));                              \
        __half2 m0_ = __hmul2(cc_, ARR[o]);                             \
        __half2 m1_ = __hmul2(cc_, ARR[o1_]);                           \
        __half2 p0_ = ARR[o1_], p1_ = ARR[o];                           \
        ARR[o]   = fma_sw(sp_, p0_, m0_);                               \
        ARR[o1_] = fma_sw(sp_, p1_, m1_); } }

#define RXDs(ARR, DPPM, I) {                                            \
    const __half2 sp_ = U2H((u32)sw[I]), cc_ = U2H((u32)cw[I]);         \
    _Pragma("unroll")                                                   \
    for (int o = 0; o < APT; ++o) {                                     \
        __half2 p_ = DPPM(ARR[o]);                                      \
        ARR[o] = fma_sw(sp_, p_, __hmul2(cc_, ARR[o])); } }

// Final DPP butterfly with the sweep write fused per pair (write tail hidden).
#define RXD_W(ARR, DPPM, I, BUF, WADDRK) {                              \
    const __half2 sp_ = U2H((u32)sw[I]), cc_ = U2H((u32)cw[I]);         \
    _Pragma("unroll")                                                   \
    for (int k = 0; k < 16; ++k) {                                      \
        __half2 p0_ = DPPM(ARR[2*k]);                                   \
        ARR[2*k]   = fma_sw(sp_, p0_, __hmul2(cc_, ARR[2*k]));          \
        __half2 p1_ = DPPM(ARR[2*k+1]);                                 \
        ARR[2*k+1] = fma_sw(sp_, p1_, __hmul2(cc_, ARR[2*k+1]));        \
        *reinterpret_cast<uint2*>((BUF) + (WADDRK)) =                   \
            make_uint2(H2U(ARR[2*k]), H2U(ARR[2*k+1])); } }

// ---- sweep o-offset tables (compile-time per unrolled index), from v11 ----
#define OW1K(k) ((((k)&1)?130:0) | (((k)&2)?260:0) | (((k)&4)?520:0) | (((k)&8)?4096:0))
#define OR1(o)  ((((o)&15)<<3) | (((o)>>4)<<13))
#define OW2K(k) ((((k)&1)?516:0) ^ (((k)&2)?1036:0) ^ (((k)&4)?2076:0) ^ (((k)&8)?4124:0))
#define OR2(o)  ((((o)&1)?24:0) ^ (((o)&2)?48:0) ^ (((o)&4)?96:0) ^ (((o)&8)?8256:0) ^ (((o)&16)?8320:0))

#define RS1(ARR, BUF) { _Pragma("unroll") for (int o = 0; o < APT; ++o) \
    ARR[o] = (BUF)[CR1 ^ OR1(o)]; }
#define RS2(ARR, BUF) { _Pragma("unroll") for (int o = 0; o < APT; ++o) \
    ARR[o] = (BUF)[CR2 ^ OR2(o)]; }

// 7-qubit RX block with fused write (RXLOW -> S1 write addr; RXHIGH -> S2).
#define RXLOW_F(ARR, BUF)  { RXQs(ARR,0,0) RXQs(ARR,1,1) RXQs(ARR,2,2)  \
    RXQs(ARR,3,3) RXQs(ARR,4,4) RXDs(ARR,DPP1,5)                        \
    RXD_W(ARR,DPP2,6,BUF,(CW1 ^ OW1K(k))) }
#define RXHIGH_F(ARR, BUF) { RXQs(ARR,0,0) RXQs(ARR,1,1) RXQs(ARR,2,2)  \
    RXQs(ARR,3,3) RXQs(ARR,4,4) RXDs(ARR,DPP1,5)                        \
    RXD_W(ARR,DPP2,6,BUF,(CW2 ^ OW2K(k))) }
#define RXHIGH_N(ARR) { RXQs(ARR,0,0) RXQs(ARR,1,1) RXQs(ARR,2,2)       \
    RXQs(ARR,3,3) RXQs(ARR,4,4) RXDs(ARR,DPP1,5) RXDs(ARR,DPP2,6) }

// Product-state encoding fused with layer-0 CNOT perm, into P0 registers.
#define ENCODE(ARR, TBL) {                                              \
    float base_ = 1.0f;                                                 \
    _Pragma("unroll") for (int q = 6; q < NQ; ++q) {                    \
        float2 f_ = (TBL)[q];                                           \
        base_ *= ((Tm >> (q - 5)) & 1) ? f_.x : f_.y; }                 \
    float2 f5_ = (TBL)[5];                                              \
    float g5a_ = (t & 1) ? f5_.x : f5_.y;                               \
    float g5b_ = (t & 1) ? f5_.y : f5_.x;                               \
    float2 f0_ = (TBL)[0], f1_ = (TBL)[1], f2_ = (TBL)[2],              \
           f3_ = (TBL)[3], f4_ = (TBL)[4];                              \
    _Pragma("unroll") for (int o = 0; o < APT; ++o) {                   \
        const int op_ = o ^ (o << 1);                                   \
        float v_ = base_ * ((op_ & 32) ? g5b_ : g5a_);                  \
        v_ *= (op_ & 1)  ? f0_.x : f0_.y;                               \
        v_ *= (op_ & 2)  ? f1_.x : f1_.y;                               \
        v_ *= (op_ & 4)  ? f2_.x : f2_.y;                               \
        v_ *= (op_ & 8)  ? f3_.x : f3_.y;                               \
        v_ *= (op_ & 16) ? f4_.x : f4_.y;                               \
        ARR[o] = __floats2half2_rn(v_, 0.0f); } }

// Z-expectation partials from P1 layout -> RED[wave*12 + 0..11]
#define EXPECT(ARR, RED) {                                              \
    float ptot = 0.f, Sq[5] = {0, 0, 0, 0, 0};                          \
    _Pragma("unroll") for (int o = 0; o < APT; ++o) {                   \
        float2 f_ = __half22float2(ARR[o]);                             \
        float p_ = f_.x * f_.x + f_.y * f_.y;                           \
        ptot += p_;                                                     \
        _Pragma("unroll") for (int m = 0; m < 5; ++m)                   \
            Sq[m] += ((o >> m) & 1) ? -p_ : p_; }                       \
    float accL[6];                                                      \
    _Pragma("unroll") for (int k = 0; k < 6; ++k) accL[k] = ptot;       \
    _Pragma("unroll") for (int k = 0; k < 6; ++k) {                     \
        _Pragma("unroll") for (int j = 0; j < 6; ++j) {                 \
            float pr_ = SHX(accL[j], k);                                \
            if (j == k) accL[j] = ((lane >> k) & 1) ? (pr_ - accL[j])   \
                                                    : (accL[j] - pr_);  \
            else accL[j] += pr_; }                                      \
        ptot += SHX(ptot, k);                                           \
        _Pragma("unroll") for (int j2 = 0; j2 < 5; ++j2)                \
            Sq[j2] += SHX(Sq[j2], k); }                                 \
    if (lane == 0) {                                                    \
        (RED)[wv * 12 + 0] = ptot;                                      \
        _Pragma("unroll") for (int k = 0; k < 6; ++k) (RED)[wv * 12 + 1 + k] = accL[k]; \
        _Pragma("unroll") for (int m2 = 0; m2 < 5; ++m2) (RED)[wv * 12 + 7 + m2] = Sq[m2]; } }

__global__ __launch_bounds__(NT, 2)
void vqc_kernel(const float* __restrict__ inputs,
                const float* __restrict__ weights,
                float* __restrict__ out)
{
    extern __shared__ __half2 lds[];   // buf0 | buf1 | wtab | itab | redA | redB
    const int t    = threadIdx.x;
    const int b    = blockIdx.x;
    const int lane = t & 63;
    const int wv   = t >> 6;
    const int sA   = 2 * b, sB = 2 * b + 1;
    const int Tm   = (t ^ (t << 1)) & 0x3FF;

    __half2* buf0 = lds;
    __half2* buf1 = lds + DIM;
    uint2*   wtab = reinterpret_cast<uint2*>(lds + 2 * DIM);   // 56
    float2*  itab = reinterpret_cast<float2*>(wtab + 56);      // 28
    float*   redA = reinterpret_cast<float*>(itab + 28);       // 96
    float*   redB = redA + 96;                                 // 96

    const int t0 = t & 1, t1 = (t >> 1) & 1, t2 = (t >> 2) & 1, t3 = (t >> 3) & 1,
              t4 = (t >> 4) & 1, t5 = (t >> 5) & 1, t6 = (t >> 6) & 1,
              t7 = (t >> 7) & 1, t8 = (t >> 8) & 1;

    // Thread-constant address bases (maps A,B; v11-validated).
    const int CW1 = ((t & 63) << 1) ^ (t6 ? 8192 : 0) ^ (t7 ? 1040 : 0) ^ (t8 ? 2048 : 0);
    const int CR1 = (t0 ? 1040 : 0) ^ (t1 ? 2048 : 0) ^ (t2 ? 1 : 0) ^ (t3 ? 130 : 0)
                  ^ (t4 ? 260 : 0) ^ (t5 ? 520 : 0) ^ (t6 ? 4096 : 0)
                  ^ (t7 ? 2 : 0) ^ (t8 ? 4 : 0);
    const int CW2 = ((t & 63) << 1) ^ (t6 ? 8192 : 0) ^ (t7 ? 128 : 0) ^ (t8 ? 258 : 0);
    const int CR2 = (t0 ? 386 : 0) ^ (t1 ? 259 : 0) ^ (t2 ? 517 : 0) ^ (t3 ? 1544 : 0)
                  ^ (t4 ? 3088 : 0) ^ (t5 ? 6144 : 0) ^ (t6 ? 4126 : 0)
                  ^ (t7 ? 6 : 0) ^ (t8 ? 4 : 0);

    // Sincos tables: wave0 does weights (sp,cc packed), wave1 does inputs.
    if (t < NL * NQ) {
        float s_, c_;
        __sincosf(0.5f * weights[t], &s_, &c_);
        wtab[t] = make_uint2(H2U(__floats2half2_rn(s_, -s_)), H2U(__float2half2_rn(c_)));
    }
    if (t >= 64 && t < 64 + 2 * NQ) {
        int i_ = t - 64;
        int si_ = (i_ >= NQ) ? 1 : 0;
        float s_, c_;
        __sincosf(0.5f * inputs[(sA + si_) * NQ + (i_ - NQ * si_)], &s_, &c_);
        itab[i_] = make_float2(s_, c_);
    }
    __syncthreads();

    int sw[7], cw[7];           // current 7-qubit coefficient block (SGPRs)
    __half2 aA[APT], aB[APT];

    PRELOADW(0, 0);
    // p0
    ENCODE(aA, itab);  RXLOW_F(aA, buf0);                       __syncthreads();
    // p1
    RS1(aA, buf0);  ENCODE(aB, itab + NQ);  RXLOW_F(aB, buf1);  PRELOADW(0, 7); __syncthreads();
    // p2
    RS1(aB, buf1);  RXHIGH_F(aA, buf0);                         __syncthreads();
    // p3
    RS2(aA, buf0);  RXHIGH_F(aB, buf1);  PRELOADW(1, 0);        __syncthreads();

#pragma unroll 1
    for (int l = 1; l < NL - 1; ++l) {
        RS2(aB, buf1);  RXLOW_F(aA, buf0);                      __syncthreads();
        RS1(aA, buf0);  RXLOW_F(aB, buf1);  PRELOADW(l, 7);     __syncthreads();
        RS1(aB, buf1);  RXHIGH_F(aA, buf0);                     __syncthreads();
        RS2(aA, buf0);  RXHIGH_F(aB, buf1); PRELOADW(l + 1, 0); __syncthreads();
    }
    // tail: layer 3
    RS2(aB, buf1);  RXLOW_F(aA, buf0);                          __syncthreads();
    RS1(aA, buf0);  RXLOW_F(aB, buf1);  PRELOADW(3, 7);         __syncthreads();
    RS1(aB, buf1);  RXHIGH_N(aA);  RXHIGH_N(aB);

    EXPECT(aA, redA);
    EXPECT(aB, redB);
    __syncthreads();

    // Cross-wave combine. P1: lane2-5 = q0-3, wave bits = q4-6, o = q7-11,
    // lane0,1 = q12,13.
    if (t < NQ) {
        float accA = 0.f, accB = 0.f;
#pragma unroll 1
        for (int w = 0; w < 8; ++w) {
            float vA, vB;
            if (t < 4)       { vA = redA[w * 12 + 3 + t];        vB = redB[w * 12 + 3 + t]; }
            else if (t < 7)  { vA = redA[w * 12];                vB = redB[w * 12];
                               if ((w >> (t - 4)) & 1) { vA = -vA; vB = -vB; } }
            else if (t < 12) { vA = redA[w * 12 + 7 + (t - 7)];  vB = redB[w * 12 + 7 + (t - 7)]; }
            else             { vA = redA[w * 12 + 1 + (t - 12)]; vB = redB[w * 12 + 1 + (t - 12)]; }
            accA += vA; accB += vB;
        }
        out[sA * NQ + t] = accA;
        out[sB * NQ + t] = accB;
    }
}

extern "C" void kernel_launch(void* const* d_in, const int* in_sizes, int n_in,
                              void* d_out, int out_size, void* d_ws, size_t ws_size,
                              hipStream_t stream)
{
    const float* inputs  = (const float*)d_in[0];
    const float* weights = (const float*)d_in[1];
    float* out = (float*)d_out;

    const int Bn = in_sizes[0] / NQ;   // 1024
    const size_t shmem = 2 * DIM * sizeof(__half2)
                       + 56 * sizeof(uint2) + 28 * sizeof(float2)
                       + 192 * sizeof(float);
    vqc_kernel<<<dim3(Bn / 2), dim3(NT), shmem, stream>>>(inputs, weights, out);
}